// Round 1
// baseline (1871.804 us; speedup 1.0000x reference)
//
#include <hip/hip_runtime.h>
#include <hip/hip_bf16.h>
#include <math.h>

// Problem constants
#define TT 32
#define NN 512
#define DD 128
#define FF_ 2048
#define HH 8
#define LL 2
#define WND_ 8
#define TOK (TT*NN)          // 16384 tokens
#define DH 16                // head dim

// ---------------------------------------------------------------------------
// Generic tiled fp32 GEMM: C[M,N] = A[M,K] @ W[N,K]^T + bias[N] (+ residual) (+relu)
// 64x64 tile, 256 threads, 4x4 outputs/thread. All M,N multiples of 64; K mult of 16.
// ---------------------------------------------------------------------------
__global__ __launch_bounds__(256) void gemm_kernel(
    const float* __restrict__ A, int lda,
    const float* __restrict__ W,             // [N,K] row-major
    const float* __restrict__ bias,          // [N]
    const float* __restrict__ R,             // residual [M,ldc] or null
    float* __restrict__ C, int ldc,
    int M, int N, int K, int relu)
{
    __shared__ float As[64][17];
    __shared__ float Ws[64][17];
    const int bm = blockIdx.y * 64;
    const int bn = blockIdx.x * 64;
    const int tid = threadIdx.x;
    const int tx = tid & 15, ty = tid >> 4;

    float acc[4][4] = {};

    for (int k0 = 0; k0 < K; k0 += 16) {
        #pragma unroll
        for (int e = tid; e < 1024; e += 256) {
            int r = e >> 4, kk = e & 15;
            As[r][kk] = A[(size_t)(bm + r) * lda + k0 + kk];
            Ws[r][kk] = W[(size_t)(bn + r) * K   + k0 + kk];
        }
        __syncthreads();
        #pragma unroll
        for (int kk = 0; kk < 16; kk++) {
            float a[4], b[4];
            #pragma unroll
            for (int i = 0; i < 4; i++) a[i] = As[ty*4+i][kk];
            #pragma unroll
            for (int j = 0; j < 4; j++) b[j] = Ws[tx*4+j][kk];
            #pragma unroll
            for (int i = 0; i < 4; i++)
                #pragma unroll
                for (int j = 0; j < 4; j++) acc[i][j] += a[i]*b[j];
        }
        __syncthreads();
    }

    #pragma unroll
    for (int i = 0; i < 4; i++) {
        int row = bm + ty*4 + i;
        #pragma unroll
        for (int j = 0; j < 4; j++) {
            int col = bn + tx*4 + j;
            float v = acc[i][j] + bias[col];
            if (R) v += R[(size_t)row * ldc + col];
            if (relu) v = fmaxf(v, 0.0f);
            C[(size_t)row * ldc + col] = v;
        }
    }
}

// ---------------------------------------------------------------------------
// Stage-1 attention: full softmax over N=512 keys, per (t,h).
// Qkv layout: [TOK, 384] token = t*NN+n; q at +0, k at +128, v at +256, head h at h*16.
// Output C: [TOK, 128].  Grid: T*H=256 blocks, 256 threads, 2 queries/thread.
// ---------------------------------------------------------------------------
__global__ __launch_bounds__(256) void attn_full_kernel(
    const float* __restrict__ Qkv, float* __restrict__ C)
{
    __shared__ float Ks[NN][DH];
    __shared__ float Vs[NN][DH];
    const int t = blockIdx.x >> 3;
    const int h = blockIdx.x & 7;
    const int tid = threadIdx.x;

    for (int e = tid; e < NN*DH; e += 256) {
        int n = e >> 4, f = e & 15;
        const float* p = Qkv + (size_t)(t*NN + n)*384 + h*DH + f;
        Ks[n][f] = p[128];
        Vs[n][f] = p[256];
    }
    __syncthreads();

    for (int qq = 0; qq < 2; qq++) {
        const int nq = tid + qq*256;
        const float* qp = Qkv + (size_t)(t*NN + nq)*384 + h*DH;
        float q[DH];
        #pragma unroll
        for (int f = 0; f < DH; f++) q[f] = qp[f] * 0.25f;  // 1/sqrt(16) folded in

        // pass 1: max score
        float m = -1e30f;
        for (int j = 0; j < NN; j++) {
            float d = 0.f;
            #pragma unroll
            for (int f = 0; f < DH; f++) d += q[f]*Ks[j][f];
            m = fmaxf(m, d);
        }
        // pass 2: exp-sum + PV
        float l = 0.f;
        float acc[DH] = {};
        for (int j = 0; j < NN; j++) {
            float d = 0.f;
            #pragma unroll
            for (int f = 0; f < DH; f++) d += q[f]*Ks[j][f];
            float p = __expf(d - m);
            l += p;
            #pragma unroll
            for (int f = 0; f < DH; f++) acc[f] += p*Vs[j][f];
        }
        float inv = 1.f / l;
        float* cp = C + (size_t)(t*NN + nq)*DD + h*DH;
        #pragma unroll
        for (int f = 0; f < DH; f++) cp[f] = acc[f]*inv;
    }
}

// ---------------------------------------------------------------------------
// Stage-3 banded attention: seq=T=32, window: j in [i-7, i]. q,k from Qkv (ld 384),
// v from Vb (ld 128). Grid: N=512 blocks; 256 threads = 8 heads x 32 queries.
// ---------------------------------------------------------------------------
__global__ __launch_bounds__(256) void attn_banded_kernel(
    const float* __restrict__ Qkv, const float* __restrict__ Vb, float* __restrict__ C)
{
    __shared__ float Qs[TT][129];
    __shared__ float Ks[TT][129];
    __shared__ float Vs[TT][129];
    const int n = blockIdx.x;
    const int tid = threadIdx.x;

    for (int e = tid; e < TT*DD; e += 256) {
        int t = e >> 7, d = e & 127;
        const float* row = Qkv + (size_t)(t*NN + n)*384;
        Qs[t][d] = row[d];
        Ks[t][d] = row[128 + d];
        Vs[t][d] = Vb[(size_t)(t*NN + n)*DD + d];
    }
    __syncthreads();

    const int h = tid >> 5, i = tid & 31;
    const int hb = h * DH;

    float s[WND_];
    #pragma unroll
    for (int kk = 0; kk < WND_; kk++) {
        int j = i - (WND_-1) + kk;
        int jc = j < 0 ? 0 : j;
        float d = 0.f;
        #pragma unroll
        for (int f = 0; f < DH; f++) d += Qs[i][hb+f]*Ks[jc][hb+f];
        s[kk] = (j >= 0) ? d*0.25f : -1e30f;
    }
    float m = s[0];
    #pragma unroll
    for (int kk = 1; kk < WND_; kk++) m = fmaxf(m, s[kk]);
    float l = 0.f, p[WND_];
    #pragma unroll
    for (int kk = 0; kk < WND_; kk++) { p[kk] = __expf(s[kk]-m); l += p[kk]; }
    float inv = 1.f / l;
    float acc[DH] = {};
    #pragma unroll
    for (int kk = 0; kk < WND_; kk++) {
        int j = i - (WND_-1) + kk;
        int jc = j < 0 ? 0 : j;
        float pw = p[kk]*inv;
        #pragma unroll
        for (int f = 0; f < DH; f++) acc[f] += pw*Vs[jc][hb+f];
    }
    float* cp = C + (size_t)(i*NN + n)*DD + hb;
    #pragma unroll
    for (int f = 0; f < DH; f++) cp[f] = acc[f];
}

// ---------------------------------------------------------------------------
// LayerNorm over D=128: Y = LN(X)*g + b. One wave per token (2 elems/lane).
// ---------------------------------------------------------------------------
__global__ __launch_bounds__(256) void ln_kernel(
    const float* __restrict__ X, const float* __restrict__ g,
    const float* __restrict__ b, float* __restrict__ Y)
{
    const int token = blockIdx.x*4 + (threadIdx.x >> 6);
    const int lane  = threadIdx.x & 63;
    const float* xr = X + (size_t)token * DD;
    float a0 = xr[lane], a1 = xr[lane + 64];
    float s = a0 + a1;
    #pragma unroll
    for (int off = 32; off > 0; off >>= 1) s += __shfl_xor(s, off);
    float mean = s * (1.0f/128.0f);
    float d0 = a0 - mean, d1 = a1 - mean;
    float v = d0*d0 + d1*d1;
    #pragma unroll
    for (int off = 32; off > 0; off >>= 1) v += __shfl_xor(v, off);
    float rstd = rsqrtf(v * (1.0f/128.0f) + 1e-5f);
    float* yr = Y + (size_t)token * DD;
    yr[lane]      = d0*rstd*g[lane]      + b[lane];
    yr[lane + 64] = d1*rstd*g[lane + 64] + b[lane + 64];
}

// ---------------------------------------------------------------------------
// time2vec add: Y[t,n,d] = x[t,n,d] + (d<127 ? sin((t+1)*w[d]+b[d]) : (t+1)*w0+b0)
// ---------------------------------------------------------------------------
__global__ __launch_bounds__(256) void t2v_add_kernel(
    const float* __restrict__ x, const float* __restrict__ w, const float* __restrict__ b,
    const float* __restrict__ w0, const float* __restrict__ b0, float* __restrict__ Y)
{
    int idx = blockIdx.x*256 + threadIdx.x;     // < TOK*DD = 2,097,152
    int d = idx & 127;
    int t = idx >> 16;                           // / (NN*DD)
    float tau = (float)(t + 1);
    float add = (d < 127) ? sinf(tau * w[d] + b[d]) : (tau * w0[0] + b0[0]);
    Y[idx] = x[idx] + add;
}

// ---------------------------------------------------------------------------
// Head: out[token] = dot(X[token,:], w[0:128]). One wave per token.
// ---------------------------------------------------------------------------
__global__ __launch_bounds__(256) void head_kernel(
    const float* __restrict__ X, const float* __restrict__ w, float* __restrict__ out)
{
    const int token = blockIdx.x*4 + (threadIdx.x >> 6);
    const int lane  = threadIdx.x & 63;
    const float* xr = X + (size_t)token * DD;
    float s = xr[lane]*w[lane] + xr[lane+64]*w[lane+64];
    #pragma unroll
    for (int off = 32; off > 0; off >>= 1) s += __shfl_xor(s, off);
    if (lane == 0) out[token] = s;
}

// ---------------------------------------------------------------------------

extern "C" void kernel_launch(void* const* d_in, const int* in_sizes, int n_in,
                              void* d_out, int out_size, void* d_ws, size_t ws_size,
                              hipStream_t stream) {
    // inputs in setup_inputs() order
    const float* x           = (const float*)d_in[0];
    const float* enc_in_w    = (const float*)d_in[1];
    const float* enc_in_b    = (const float*)d_in[2];
    const float* enc_out_w   = (const float*)d_in[3];
    const float* enc_out_b   = (const float*)d_in[4];
    const float* enc_l1w     = (const float*)d_in[5];
    const float* enc_l1b     = (const float*)d_in[6];
    const float* enc_l2w     = (const float*)d_in[7];
    const float* enc_l2b     = (const float*)d_in[8];
    const float* enc_ln1w    = (const float*)d_in[9];
    const float* enc_ln1b    = (const float*)d_in[10];
    const float* enc_ln2w    = (const float*)d_in[11];
    const float* enc_ln2b    = (const float*)d_in[12];
    const float* qk_in_w     = (const float*)d_in[13];
    const float* qk_in_b     = (const float*)d_in[14];
    const float* qk_out_w    = (const float*)d_in[15];
    const float* qk_out_b    = (const float*)d_in[16];
    const float* qk_l1w      = (const float*)d_in[17];
    const float* qk_l1b      = (const float*)d_in[18];
    const float* qk_l2w      = (const float*)d_in[19];
    const float* qk_l2b      = (const float*)d_in[20];
    const float* qk_ln1w     = (const float*)d_in[21];
    const float* qk_ln1b     = (const float*)d_in[22];
    const float* qk_ln2w     = (const float*)d_in[23];
    const float* qk_ln2b     = (const float*)d_in[24];
    const float* t2v_w       = (const float*)d_in[25];
    const float* t2v_b       = (const float*)d_in[26];
    const float* t2v_w0      = (const float*)d_in[27];
    const float* t2v_b0      = (const float*)d_in[28];
    const float* out_w       = (const float*)d_in[29];
    float* out = (float*)d_out;

    // workspace layout (floats)
    float* ws = (float*)d_ws;
    const size_t TOKD = (size_t)TOK * DD;       // 2,097,152
    float* bufA = ws;                           // residual stream
    float* tmpB = bufA + TOKD;                  // pre-LN buffer
    float* Zb   = tmpB + TOKD;                  // outs_zs
    float* Vb   = Zb   + TOKD;                  // v-projection (qk layers)
    float* Cb   = Vb   + TOKD;                  // attention context
    float* Qb   = Cb   + TOKD;                  // qkv [TOK,384]
    float* Hb   = Qb   + (size_t)TOK * 384;     // FFN hidden chunk
    size_t base_floats = (size_t)(Hb - ws);
    size_t ws_floats = ws_size / sizeof(float);
    size_t availH = ws_floats > base_floats ? ws_floats - base_floats : 0;
    int Mc = (int)((availH / FF_) & ~(size_t)63);      // tokens per FFN chunk
    if (Mc > TOK) Mc = TOK;
    if (Mc < 64) Mc = 64;                              // last-resort (ws too small)

    auto gemm = [&](const float* A, int lda, const float* W, const float* bias,
                    const float* R, float* C, int ldc, int M, int N, int K, int relu) {
        dim3 grid(N/64, M/64);
        gemm_kernel<<<grid, 256, 0, stream>>>(A, lda, W, bias, R, C, ldc, M, N, K, relu);
    };

    // ---------------- stage 1: plain encoder (attend over N, batch T) --------
    gemm(x, DD, enc_in_w, enc_in_b, nullptr, Qb, 384, TOK, 384, DD, 0);
    attn_full_kernel<<<TT*HH, 256, 0, stream>>>(Qb, Cb);
    gemm(Cb, DD, enc_out_w, enc_out_b, x, tmpB, DD, TOK, DD, DD, 0);
    ln_kernel<<<TOK/4, 256, 0, stream>>>(tmpB, enc_ln1w, enc_ln1b, bufA);
    for (int c0 = 0; c0 < TOK; c0 += Mc) {
        int cm = (TOK - c0) < Mc ? (TOK - c0) : Mc;
        gemm(bufA + (size_t)c0*DD, DD, enc_l1w, enc_l1b, nullptr, Hb, FF_, cm, FF_, DD, 1);
        gemm(Hb, FF_, enc_l2w, enc_l2b, bufA + (size_t)c0*DD,
             tmpB + (size_t)c0*DD, DD, cm, DD, FF_, 0);
    }
    ln_kernel<<<TOK/4, 256, 0, stream>>>(tmpB, enc_ln2w, enc_ln2b, Zb);   // outs_zs

    // ---------------- stage 2: time2vec ------------------------------------
    t2v_add_kernel<<<(TOK*DD)/256, 256, 0, stream>>>(x, t2v_w, t2v_b, t2v_w0, t2v_b0, bufA);

    // ---------------- stage 3: qk encoder stack (banded window attn) --------
    for (int l = 0; l < LL; l++) {
        const float* iw  = qk_in_w  + (size_t)l*384*DD;
        const float* ib  = qk_in_b  + (size_t)l*384;
        const float* ow  = qk_out_w + (size_t)l*DD*DD;
        const float* ob  = qk_out_b + (size_t)l*DD;
        const float* l1w = qk_l1w   + (size_t)l*FF_*DD;
        const float* l1b = qk_l1b   + (size_t)l*FF_;
        const float* l2w = qk_l2w   + (size_t)l*DD*FF_;
        const float* l2b = qk_l2b   + (size_t)l*DD;

        // q,k from stream; v from outs_zs
        gemm(bufA, DD, iw, ib, nullptr, Qb, 384, TOK, 256, DD, 0);
        gemm(Zb,   DD, iw + (size_t)256*DD, ib + 256, nullptr, Vb, DD, TOK, DD, DD, 0);
        attn_banded_kernel<<<NN, 256, 0, stream>>>(Qb, Vb, Cb);
        gemm(Cb, DD, ow, ob, bufA, tmpB, DD, TOK, DD, DD, 0);
        ln_kernel<<<TOK/4, 256, 0, stream>>>(tmpB, qk_ln1w + l*DD, qk_ln1b + l*DD, bufA);
        for (int c0 = 0; c0 < TOK; c0 += Mc) {
            int cm = (TOK - c0) < Mc ? (TOK - c0) : Mc;
            gemm(bufA + (size_t)c0*DD, DD, l1w, l1b, nullptr, Hb, FF_, cm, FF_, DD, 1);
            gemm(Hb, FF_, l2w, l2b, bufA + (size_t)c0*DD,
                 tmpB + (size_t)c0*DD, DD, cm, DD, FF_, 0);
        }
        ln_kernel<<<TOK/4, 256, 0, stream>>>(tmpB, qk_ln2w + l*DD, qk_ln2b + l*DD, bufA);
    }

    // ---------------- head ---------------------------------------------------
    head_kernel<<<TOK/4, 256, 0, stream>>>(bufA, out_w, out);
}

// Round 2
// 541.313 us; speedup vs baseline: 3.4579x; 3.4579x over previous
//
#include <hip/hip_runtime.h>
#include <hip/hip_bf16.h>
#include <math.h>

// Problem constants
#define TT 32
#define NN 512
#define DD 128
#define FF_ 2048
#define HH 8
#define LL 2
#define WND_ 8
#define TOK (TT*NN)          // 16384 tokens
#define DH 16                // head dim

typedef __hip_bfloat16 bf16;
typedef __attribute__((ext_vector_type(8))) short bf16x8;   // 8 bf16 (4 VGPRs)
typedef __attribute__((ext_vector_type(4))) float f32x4;    // 4 fp32

// global_load_lds: 16B per lane, LDS dest = wave-uniform base + lane*16 (linear)
#define GLD_LDS16(gp, lp) __builtin_amdgcn_global_load_lds( \
    (const __attribute__((address_space(1))) unsigned int*)(gp), \
    (__attribute__((address_space(3))) unsigned int*)(lp), 16, 0, 0)

__device__ inline void store_out(float* p, float v) { *p = v; }
__device__ inline void store_out(bf16* p, float v) { *p = __float2bfloat16(v); }

// ---------------------------------------------------------------------------
// bf16 MFMA GEMM: C[M,N] = A[M,K](bf16) @ W[N,K](bf16)^T + bias (+ bf16 residual) (+relu)
// Tile BM x BN, BK=32, 256 threads = 4 waves in 2x2, each wave (BM/2)x(BN/2).
// M % BM == 0, N % BN == 0, K % 32 == 0.
// ---------------------------------------------------------------------------
template<int BM, int BN, typename OutT>
__global__ __launch_bounds__(256) void mfma_gemm(
    const bf16* __restrict__ A, int lda,
    const bf16* __restrict__ W,              // [N,K] row-major (= B^T)
    const float* __restrict__ bias,          // [N]
    const bf16* __restrict__ R,              // residual [M,ldc] bf16 or null
    OutT* __restrict__ C, int ldc,
    int K, int relu)
{
    constexpr int WM = BM / 2, WN = BN / 2;
    constexpr int FM = WM / 16, FN = WN / 16;
    constexpr int LA = (BM * 64) / (256 * 16);   // 16B loads per thread for A tile
    constexpr int LB = (BN * 64) / (256 * 16);

    __shared__ bf16 As[BM * 32];
    __shared__ bf16 Bs[BN * 32];

    const int tid  = threadIdx.x;
    const int lane = tid & 63;
    const int wave = tid >> 6;
    const int wm = wave >> 1, wn = wave & 1;
    const int bm = blockIdx.y * BM, bn = blockIdx.x * BN;

    f32x4 acc[FM][FN];
    #pragma unroll
    for (int m = 0; m < FM; m++)
        #pragma unroll
        for (int n = 0; n < FN; n++)
            acc[m][n] = (f32x4){0.f, 0.f, 0.f, 0.f};

    for (int k0 = 0; k0 < K; k0 += 32) {
        // stage A tile [BM][32] bf16, linear
        #pragma unroll
        for (int i = 0; i < LA; i++) {
            const int o = (tid + i * 256) * 16;       // byte offset in As
            const int row = o >> 6;                   // 64 B per row
            const int ce  = (o & 63) >> 1;            // element col
            GLD_LDS16(A + (size_t)(bm + row) * lda + k0 + ce, (char*)As + o);
        }
        // stage B tile [BN][32] bf16, linear
        #pragma unroll
        for (int i = 0; i < LB; i++) {
            const int o = (tid + i * 256) * 16;
            const int row = o >> 6;
            const int ce  = (o & 63) >> 1;
            GLD_LDS16(W + (size_t)(bn + row) * K + k0 + ce, (char*)Bs + o);
        }
        __syncthreads();   // drains vmcnt -> LDS data visible

        bf16x8 af[FM], bfr[FN];
        #pragma unroll
        for (int m = 0; m < FM; m++)
            af[m] = *(const bf16x8*)(As + (wm * WM + m * 16 + (lane & 15)) * 32 + (lane >> 4) * 8);
        #pragma unroll
        for (int n = 0; n < FN; n++)
            bfr[n] = *(const bf16x8*)(Bs + (wn * WN + n * 16 + (lane & 15)) * 32 + (lane >> 4) * 8);
        #pragma unroll
        for (int m = 0; m < FM; m++)
            #pragma unroll
            for (int n = 0; n < FN; n++)
                acc[m][n] = __builtin_amdgcn_mfma_f32_16x16x32_bf16(af[m], bfr[n], acc[m][n], 0, 0, 0);
        __syncthreads();
    }

    // epilogue: C/D layout col = lane&15, row = (lane>>4)*4 + reg   [m89]
    #pragma unroll
    for (int n = 0; n < FN; n++) {
        const int col = bn + wn * WN + n * 16 + (lane & 15);
        const float bv = bias[col];
        #pragma unroll
        for (int m = 0; m < FM; m++) {
            #pragma unroll
            for (int r = 0; r < 4; r++) {
                const int row = bm + wm * WM + m * 16 + (lane >> 4) * 4 + r;
                float v = acc[m][n][r] + bv;
                if (R) v += __bfloat162float(R[(size_t)row * ldc + col]);
                if (relu) v = fmaxf(v, 0.f);
                store_out(&C[(size_t)row * ldc + col], v);
            }
        }
    }
}

// ---------------------------------------------------------------------------
// fp32 -> bf16 conversion, 4 elems/thread
// ---------------------------------------------------------------------------
__global__ __launch_bounds__(256) void f2b_kernel(const float* __restrict__ X,
                                                  bf16* __restrict__ Y, int n4)
{
    int i = blockIdx.x * 256 + threadIdx.x;
    if (i < n4) {
        float4 v = ((const float4*)X)[i];
        bf16* y = Y + (size_t)i * 4;
        y[0] = __float2bfloat16(v.x);
        y[1] = __float2bfloat16(v.y);
        y[2] = __float2bfloat16(v.z);
        y[3] = __float2bfloat16(v.w);
    }
}

// ---------------------------------------------------------------------------
// Stage-1 attention: full softmax over N=512 keys, per (t,h). fp32 in, bf16 out.
// ---------------------------------------------------------------------------
__global__ __launch_bounds__(256) void attn_full_kernel(
    const float* __restrict__ Qkv, bf16* __restrict__ C)
{
    __shared__ float Ks[NN][DH];
    __shared__ float Vs[NN][DH];
    const int t = blockIdx.x >> 3;
    const int h = blockIdx.x & 7;
    const int tid = threadIdx.x;

    for (int e = tid; e < NN * DH; e += 256) {
        int n = e >> 4, f = e & 15;
        const float* p = Qkv + (size_t)(t * NN + n) * 384 + h * DH + f;
        Ks[n][f] = p[128];
        Vs[n][f] = p[256];
    }
    __syncthreads();

    for (int qq = 0; qq < 2; qq++) {
        const int nq = tid + qq * 256;
        const float* qp = Qkv + (size_t)(t * NN + nq) * 384 + h * DH;
        float q[DH];
        #pragma unroll
        for (int f = 0; f < DH; f++) q[f] = qp[f] * 0.25f;  // 1/sqrt(16)

        float m = -1e30f;
        for (int j = 0; j < NN; j++) {
            float d = 0.f;
            #pragma unroll
            for (int f = 0; f < DH; f++) d += q[f] * Ks[j][f];
            m = fmaxf(m, d);
        }
        float l = 0.f;
        float acc[DH] = {};
        for (int j = 0; j < NN; j++) {
            float d = 0.f;
            #pragma unroll
            for (int f = 0; f < DH; f++) d += q[f] * Ks[j][f];
            float p = __expf(d - m);
            l += p;
            #pragma unroll
            for (int f = 0; f < DH; f++) acc[f] += p * Vs[j][f];
        }
        float inv = 1.f / l;
        bf16* cp = C + (size_t)(t * NN + nq) * DD + h * DH;
        #pragma unroll
        for (int f = 0; f < DH; f++) cp[f] = __float2bfloat16(acc[f] * inv);
    }
}

// ---------------------------------------------------------------------------
// Stage-3 banded attention: window j in [i-7, i]. fp32 q/k/v in, bf16 out.
// ---------------------------------------------------------------------------
__global__ __launch_bounds__(256) void attn_banded_kernel(
    const float* __restrict__ Qkv, const float* __restrict__ Vb, bf16* __restrict__ C)
{
    __shared__ float Qs[TT][129];
    __shared__ float Ks[TT][129];
    __shared__ float Vs[TT][129];
    const int n = blockIdx.x;
    const int tid = threadIdx.x;

    for (int e = tid; e < TT * DD; e += 256) {
        int t = e >> 7, d = e & 127;
        const float* row = Qkv + (size_t)(t * NN + n) * 384;
        Qs[t][d] = row[d];
        Ks[t][d] = row[128 + d];
        Vs[t][d] = Vb[(size_t)(t * NN + n) * DD + d];
    }
    __syncthreads();

    const int h = tid >> 5, i = tid & 31;
    const int hb = h * DH;

    float s[WND_];
    #pragma unroll
    for (int kk = 0; kk < WND_; kk++) {
        int j = i - (WND_ - 1) + kk;
        int jc = j < 0 ? 0 : j;
        float d = 0.f;
        #pragma unroll
        for (int f = 0; f < DH; f++) d += Qs[i][hb + f] * Ks[jc][hb + f];
        s[kk] = (j >= 0) ? d * 0.25f : -1e30f;
    }
    float m = s[0];
    #pragma unroll
    for (int kk = 1; kk < WND_; kk++) m = fmaxf(m, s[kk]);
    float l = 0.f, p[WND_];
    #pragma unroll
    for (int kk = 0; kk < WND_; kk++) { p[kk] = __expf(s[kk] - m); l += p[kk]; }
    float inv = 1.f / l;
    float acc[DH] = {};
    #pragma unroll
    for (int kk = 0; kk < WND_; kk++) {
        int j = i - (WND_ - 1) + kk;
        int jc = j < 0 ? 0 : j;
        float pw = p[kk] * inv;
        #pragma unroll
        for (int f = 0; f < DH; f++) acc[f] += pw * Vs[jc][hb + f];
    }
    bf16* cp = C + (size_t)(i * NN + n) * DD + hb;
    #pragma unroll
    for (int f = 0; f < DH; f++) cp[f] = __float2bfloat16(acc[f]);
}

// ---------------------------------------------------------------------------
// LayerNorm over D=128, fp32 in -> bf16 out. One wave per token.
// ---------------------------------------------------------------------------
__global__ __launch_bounds__(256) void ln_kernel(
    const float* __restrict__ X, const float* __restrict__ g,
    const float* __restrict__ b, bf16* __restrict__ Y)
{
    const int token = blockIdx.x * 4 + (threadIdx.x >> 6);
    const int lane  = threadIdx.x & 63;
    const float* xr = X + (size_t)token * DD;
    float a0 = xr[lane], a1 = xr[lane + 64];
    float s = a0 + a1;
    #pragma unroll
    for (int off = 32; off > 0; off >>= 1) s += __shfl_xor(s, off);
    float mean = s * (1.0f / 128.0f);
    float d0 = a0 - mean, d1 = a1 - mean;
    float v = d0 * d0 + d1 * d1;
    #pragma unroll
    for (int off = 32; off > 0; off >>= 1) v += __shfl_xor(v, off);
    float rstd = rsqrtf(v * (1.0f / 128.0f) + 1e-5f);
    bf16* yr = Y + (size_t)token * DD;
    yr[lane]      = __float2bfloat16(d0 * rstd * g[lane]      + b[lane]);
    yr[lane + 64] = __float2bfloat16(d1 * rstd * g[lane + 64] + b[lane + 64]);
}

// ---------------------------------------------------------------------------
// time2vec add: bf16 out
// ---------------------------------------------------------------------------
__global__ __launch_bounds__(256) void t2v_add_kernel(
    const float* __restrict__ x, const float* __restrict__ w, const float* __restrict__ b,
    const float* __restrict__ w0, const float* __restrict__ b0, bf16* __restrict__ Y)
{
    int idx = blockIdx.x * 256 + threadIdx.x;   // < TOK*DD
    int d = idx & 127;
    int t = idx >> 16;                           // / (NN*DD)
    float tau = (float)(t + 1);
    float add = (d < 127) ? sinf(tau * w[d] + b[d]) : (tau * w0[0] + b0[0]);
    Y[idx] = __float2bfloat16(x[idx] + add);
}

// ---------------------------------------------------------------------------
// Head: out[token] = dot(X[token,:], w). bf16 X, fp32 out.
// ---------------------------------------------------------------------------
__global__ __launch_bounds__(256) void head_kernel(
    const bf16* __restrict__ X, const float* __restrict__ w, float* __restrict__ out)
{
    const int token = blockIdx.x * 4 + (threadIdx.x >> 6);
    const int lane  = threadIdx.x & 63;
    const bf16* xr = X + (size_t)token * DD;
    float s = __bfloat162float(xr[lane]) * w[lane]
            + __bfloat162float(xr[lane + 64]) * w[lane + 64];
    #pragma unroll
    for (int off = 32; off > 0; off >>= 1) s += __shfl_xor(s, off);
    if (lane == 0) out[token] = s;
}

// ---------------------------------------------------------------------------

extern "C" void kernel_launch(void* const* d_in, const int* in_sizes, int n_in,
                              void* d_out, int out_size, void* d_ws, size_t ws_size,
                              hipStream_t stream) {
    const float* x           = (const float*)d_in[0];
    const float* enc_in_w    = (const float*)d_in[1];
    const float* enc_in_b    = (const float*)d_in[2];
    const float* enc_out_w   = (const float*)d_in[3];
    const float* enc_out_b   = (const float*)d_in[4];
    const float* enc_l1w     = (const float*)d_in[5];
    const float* enc_l1b     = (const float*)d_in[6];
    const float* enc_l2w     = (const float*)d_in[7];
    const float* enc_l2b     = (const float*)d_in[8];
    const float* enc_ln1w    = (const float*)d_in[9];
    const float* enc_ln1b    = (const float*)d_in[10];
    const float* enc_ln2w    = (const float*)d_in[11];
    const float* enc_ln2b    = (const float*)d_in[12];
    const float* qk_in_w     = (const float*)d_in[13];
    const float* qk_in_b     = (const float*)d_in[14];
    const float* qk_out_w    = (const float*)d_in[15];
    const float* qk_out_b    = (const float*)d_in[16];
    const float* qk_l1w      = (const float*)d_in[17];
    const float* qk_l1b      = (const float*)d_in[18];
    const float* qk_l2w      = (const float*)d_in[19];
    const float* qk_l2b      = (const float*)d_in[20];
    const float* qk_ln1w     = (const float*)d_in[21];
    const float* qk_ln1b     = (const float*)d_in[22];
    const float* qk_ln2w     = (const float*)d_in[23];
    const float* qk_ln2b     = (const float*)d_in[24];
    const float* t2v_w       = (const float*)d_in[25];
    const float* t2v_b       = (const float*)d_in[26];
    const float* t2v_w0      = (const float*)d_in[27];
    const float* t2v_b0      = (const float*)d_in[28];
    const float* out_w       = (const float*)d_in[29];
    float* out = (float*)d_out;

    // ---------------- workspace layout (bytes) ------------------------------
    char* ws = (char*)d_ws;
    const size_t TOKD = (size_t)TOK * DD;        // 2,097,152 elements
    size_t off = 0;
    auto alloc = [&](size_t bytes) { char* p = ws + off; off += (bytes + 255) & ~(size_t)255; return p; };

    float* tmpB = (float*)alloc(TOKD * 4);             // pre-LN fp32
    float* Qb   = (float*)alloc((size_t)TOK * 384 * 4);// qkv fp32
    float* Vb   = (float*)alloc(TOKD * 4);             // v-projection fp32
    bf16*  xb   = (bf16*)alloc(TOKD * 2);              // bf16 copy of x
    bf16*  bufA = (bf16*)alloc(TOKD * 2);              // residual stream bf16
    bf16*  Zb   = (bf16*)alloc(TOKD * 2);              // outs_zs bf16
    bf16*  Cb   = (bf16*)alloc(TOKD * 2);              // attn context bf16
    // weight bf16 buffers
    bf16* enc_in_wb  = (bf16*)alloc(384 * DD * 2);
    bf16* enc_out_wb = (bf16*)alloc(DD * DD * 2);
    bf16* enc_l1wb   = (bf16*)alloc((size_t)FF_ * DD * 2);
    bf16* enc_l2wb   = (bf16*)alloc((size_t)DD * FF_ * 2);
    bf16* qk_in_wb   = (bf16*)alloc((size_t)LL * 384 * DD * 2);
    bf16* qk_out_wb  = (bf16*)alloc((size_t)LL * DD * DD * 2);
    bf16* qk_l1wb    = (bf16*)alloc((size_t)LL * FF_ * DD * 2);
    bf16* qk_l2wb    = (bf16*)alloc((size_t)LL * DD * FF_ * 2);
    bf16* Hb = (bf16*)(ws + off);                      // FFN hidden chunk (bf16)
    size_t avail = ws_size > off ? ws_size - off : 0;
    int Mc = (int)((avail / ((size_t)FF_ * 2)) & ~(size_t)127);
    if (Mc > TOK) Mc = TOK;
    if (Mc < 128) Mc = 128;

    // ---------------- convert weights + x to bf16 ---------------------------
    auto conv = [&](const float* src, bf16* dst, size_t n) {
        int n4 = (int)(n / 4);
        f2b_kernel<<<(n4 + 255) / 256, 256, 0, stream>>>(src, dst, n4);
    };
    conv(x, xb, TOKD);
    conv(enc_in_w,  enc_in_wb,  384 * DD);
    conv(enc_out_w, enc_out_wb, DD * DD);
    conv(enc_l1w,   enc_l1wb,   (size_t)FF_ * DD);
    conv(enc_l2w,   enc_l2wb,   (size_t)DD * FF_);
    conv(qk_in_w,   qk_in_wb,   (size_t)LL * 384 * DD);
    conv(qk_out_w,  qk_out_wb,  (size_t)LL * DD * DD);
    conv(qk_l1w,    qk_l1wb,    (size_t)LL * FF_ * DD);
    conv(qk_l2w,    qk_l2wb,    (size_t)LL * DD * FF_);

    // GEMM launchers
    auto gemm128 = [&]<typename OutT>(const bf16* A, int lda, const bf16* W, const float* bias,
                       const bf16* R, OutT* C, int ldc, int M, int N, int K, int relu) {
        dim3 grid(N / 128, M / 128);
        mfma_gemm<128, 128, OutT><<<grid, 256, 0, stream>>>(A, lda, W, bias, R, C, ldc, K, relu);
    };
    auto gemm64 = [&]<typename OutT>(const bf16* A, int lda, const bf16* W, const float* bias,
                      const bf16* R, OutT* C, int ldc, int M, int N, int K, int relu) {
        dim3 grid(N / 64, M / 64);
        mfma_gemm<64, 64, OutT><<<grid, 256, 0, stream>>>(A, lda, W, bias, R, C, ldc, K, relu);
    };

    // ---------------- stage 1: plain encoder (attend over N, batch T) -------
    gemm128(xb, DD, enc_in_wb, enc_in_b, (const bf16*)nullptr, Qb, 384, TOK, 384, DD, 0);
    attn_full_kernel<<<TT * HH, 256, 0, stream>>>(Qb, Cb);
    gemm64(Cb, DD, enc_out_wb, enc_out_b, xb, tmpB, DD, TOK, DD, DD, 0);
    ln_kernel<<<TOK / 4, 256, 0, stream>>>(tmpB, enc_ln1w, enc_ln1b, bufA);
    for (int c0 = 0; c0 < TOK; c0 += Mc) {
        int cm = (TOK - c0) < Mc ? (TOK - c0) : Mc;
        gemm128(bufA + (size_t)c0 * DD, DD, enc_l1wb, enc_l1b, (const bf16*)nullptr, Hb, FF_, cm, FF_, DD, 1);
        gemm64(Hb, FF_, enc_l2wb, enc_l2b, bufA + (size_t)c0 * DD,
               tmpB + (size_t)c0 * DD, DD, cm, DD, FF_, 0);
    }
    ln_kernel<<<TOK / 4, 256, 0, stream>>>(tmpB, enc_ln2w, enc_ln2b, Zb);   // outs_zs

    // ---------------- stage 2: time2vec -------------------------------------
    t2v_add_kernel<<<(TOK * DD) / 256, 256, 0, stream>>>(x, t2v_w, t2v_b, t2v_w0, t2v_b0, bufA);

    // ---------------- stage 3: qk encoder stack (banded window attn) ---------
    for (int l = 0; l < LL; l++) {
        const bf16* iw   = qk_in_wb  + (size_t)l * 384 * DD;
        const float* ib  = qk_in_b   + (size_t)l * 384;
        const bf16* owt  = qk_out_wb + (size_t)l * DD * DD;
        const float* ob  = qk_out_b  + (size_t)l * DD;
        const bf16* l1w  = qk_l1wb   + (size_t)l * FF_ * DD;
        const float* l1b = qk_l1b    + (size_t)l * FF_;
        const bf16* l2w  = qk_l2wb   + (size_t)l * DD * FF_;
        const float* l2b = qk_l2b    + (size_t)l * DD;

        // q,k (first 256 rows of in_proj) from stream; v (last 128 rows) from outs_zs
        gemm128(bufA, DD, iw, ib, (const bf16*)nullptr, Qb, 384, TOK, 256, DD, 0);
        gemm64(Zb, DD, iw + (size_t)256 * DD, ib + 256, (const bf16*)nullptr, Vb, DD, TOK, DD, DD, 0);
        attn_banded_kernel<<<NN, 256, 0, stream>>>(Qb, Vb, Cb);
        gemm64(Cb, DD, owt, ob, bufA, tmpB, DD, TOK, DD, DD, 0);
        ln_kernel<<<TOK / 4, 256, 0, stream>>>(tmpB, qk_ln1w + l * DD, qk_ln1b + l * DD, bufA);
        for (int c0 = 0; c0 < TOK; c0 += Mc) {
            int cm = (TOK - c0) < Mc ? (TOK - c0) : Mc;
            gemm128(bufA + (size_t)c0 * DD, DD, l1w, l1b, (const bf16*)nullptr, Hb, FF_, cm, FF_, DD, 1);
            gemm64(Hb, FF_, l2w, l2b, bufA + (size_t)c0 * DD,
                   tmpB + (size_t)c0 * DD, DD, cm, DD, FF_, 0);
        }
        ln_kernel<<<TOK / 4, 256, 0, stream>>>(tmpB, qk_ln2w + l * DD, qk_ln2b + l * DD, bufA);
    }

    // ---------------- head ----------------------------------------------------
    head_kernel<<<TOK / 4, 256, 0, stream>>>(bufA, out_w, out);
}

// Round 4
// 365.757 us; speedup vs baseline: 5.1176x; 1.4800x over previous
//
#include <hip/hip_runtime.h>
#include <hip/hip_bf16.h>
#include <math.h>

// Problem constants
#define TT 32
#define NN 512
#define DD 128
#define FF_ 2048
#define HH 8
#define LL 2
#define WND_ 8
#define TOK (TT*NN)          // 16384 tokens
#define DH 16                // head dim

typedef __hip_bfloat16 bf16;
typedef __attribute__((ext_vector_type(8))) short bf16x8;   // 8 bf16 (4 VGPRs)
typedef __attribute__((ext_vector_type(4))) float f32x4;    // 4 fp32

// global_load_lds: 16B per lane, LDS dest = wave-uniform base + lane*16 (linear)
#define GLD_LDS16(gp, lp) __builtin_amdgcn_global_load_lds( \
    (const __attribute__((address_space(1))) unsigned int*)(gp), \
    (__attribute__((address_space(3))) unsigned int*)(lp), 16, 0, 0)

__device__ inline void store_out(float* p, float v) { *p = v; }
__device__ inline void store_out(bf16* p, float v) { *p = __float2bfloat16(v); }
__device__ inline short f2bs(float f) {
    __hip_bfloat16 h = __float2bfloat16(f);
    return *reinterpret_cast<short*>(&h);
}

// ---------------------------------------------------------------------------
// bf16 MFMA GEMM: C[M,N] = A[M,K](bf16) @ W[N,K](bf16)^T + bias (+ bf16 residual) (+relu)
// Tile BM x BN, BK=32, 256 threads = 4 waves in 2x2, each wave (BM/2)x(BN/2).
// ---------------------------------------------------------------------------
template<int BM, int BN, typename OutT>
__global__ __launch_bounds__(256) void mfma_gemm(
    const bf16* __restrict__ A, int lda,
    const bf16* __restrict__ W,              // [N,K] row-major (= B^T)
    const float* __restrict__ bias,          // [N]
    const bf16* __restrict__ R,              // residual [M,ldc] bf16 or null
    OutT* __restrict__ C, int ldc,
    int K, int relu)
{
    constexpr int WM = BM / 2, WN = BN / 2;
    constexpr int FM = WM / 16, FN = WN / 16;
    constexpr int LA = (BM * 64) / (256 * 16);
    constexpr int LB = (BN * 64) / (256 * 16);

    __shared__ bf16 As[BM * 32];
    __shared__ bf16 Bs[BN * 32];

    const int tid  = threadIdx.x;
    const int lane = tid & 63;
    const int wave = tid >> 6;
    const int wm = wave >> 1, wn = wave & 1;
    const int bm = blockIdx.y * BM, bn = blockIdx.x * BN;

    f32x4 acc[FM][FN];
    #pragma unroll
    for (int m = 0; m < FM; m++)
        #pragma unroll
        for (int n = 0; n < FN; n++)
            acc[m][n] = (f32x4){0.f, 0.f, 0.f, 0.f};

    for (int k0 = 0; k0 < K; k0 += 32) {
        #pragma unroll
        for (int i = 0; i < LA; i++) {
            const int o = (tid + i * 256) * 16;
            const int row = o >> 6;
            const int ce  = (o & 63) >> 1;
            GLD_LDS16(A + (size_t)(bm + row) * lda + k0 + ce, (char*)As + o);
        }
        #pragma unroll
        for (int i = 0; i < LB; i++) {
            const int o = (tid + i * 256) * 16;
            const int row = o >> 6;
            const int ce  = (o & 63) >> 1;
            GLD_LDS16(W + (size_t)(bn + row) * K + k0 + ce, (char*)Bs + o);
        }
        __syncthreads();

        bf16x8 af[FM], bfr[FN];
        #pragma unroll
        for (int m = 0; m < FM; m++)
            af[m] = *(const bf16x8*)(As + (wm * WM + m * 16 + (lane & 15)) * 32 + (lane >> 4) * 8);
        #pragma unroll
        for (int n = 0; n < FN; n++)
            bfr[n] = *(const bf16x8*)(Bs + (wn * WN + n * 16 + (lane & 15)) * 32 + (lane >> 4) * 8);
        #pragma unroll
        for (int m = 0; m < FM; m++)
            #pragma unroll
            for (int n = 0; n < FN; n++)
                acc[m][n] = __builtin_amdgcn_mfma_f32_16x16x32_bf16(af[m], bfr[n], acc[m][n], 0, 0, 0);
        __syncthreads();
    }

    #pragma unroll
    for (int n = 0; n < FN; n++) {
        const int col = bn + wn * WN + n * 16 + (lane & 15);
        const float bv = bias[col];
        #pragma unroll
        for (int m = 0; m < FM; m++) {
            #pragma unroll
            for (int r = 0; r < 4; r++) {
                const int row = bm + wm * WM + m * 16 + (lane >> 4) * 4 + r;
                float v = acc[m][n][r] + bv;
                if (R) v += __bfloat162float(R[(size_t)row * ldc + col]);
                if (relu) v = fmaxf(v, 0.f);
                store_out(&C[(size_t)row * ldc + col], v);
            }
        }
    }
}

// ---------------------------------------------------------------------------
// fp32 -> bf16 conversion, 4 elems/thread
// ---------------------------------------------------------------------------
__global__ __launch_bounds__(256) void f2b_kernel(const float* __restrict__ X,
                                                  bf16* __restrict__ Y, int n4)
{
    int i = blockIdx.x * 256 + threadIdx.x;
    if (i < n4) {
        float4 v = ((const float4*)X)[i];
        bf16* y = Y + (size_t)i * 4;
        y[0] = __float2bfloat16(v.x);
        y[1] = __float2bfloat16(v.y);
        y[2] = __float2bfloat16(v.z);
        y[3] = __float2bfloat16(v.w);
    }
}

// ---------------------------------------------------------------------------
// Stage-1 attention via MFMA (flash, maxless). One block per (t,h).
// Qkv: bf16 [TOK][384] (q +0, k +128, v +256; head h at h*16). C: bf16 [TOK][128].
// 4 waves x 128 queries. LDS: Q[512][16], K[512][16] bf16 (K-dim padded to 32
// via broadcast zero block on lane-groups 2,3), Vt[16][520].
// Swapped QK^T: S^T = mfma(Kfrag, Qfrag) with key rows fed pi-permuted so the
// accumulator key layout (8g+r) matches the PV A-fragment (8 consecutive keys
// per lane-group) -> no shuffles for P. Each kt iteration covers 32 keys
// (2 score MFMAs + 1 PV MFMA) => kt in [0,16).
// Maxless softmax: |s| < ~0.4 for this data; exp2 with folded 0.25*log2(e).
// ---------------------------------------------------------------------------
__global__ __launch_bounds__(256) void attn_full_mfma(
    const bf16* __restrict__ Qkv, bf16* __restrict__ C)
{
    __shared__ bf16 Qs[512 * 16];
    __shared__ bf16 Ks[512 * 16];
    __shared__ bf16 Vt[16 * 520];
    __shared__ bf16 Zero[32];          // 64B broadcast zero block

    const int t = blockIdx.x >> 3;
    const int h = blockIdx.x & 7;
    const int tid = threadIdx.x;

    if (tid < 32) ((unsigned short*)Zero)[tid] = 0;

    for (int n = tid; n < 512; n += 256) {
        const unsigned short* row = (const unsigned short*)Qkv + (size_t)(t * 512 + n) * 384 + h * 16;
        uint4 q0 = *(const uint4*)(row);
        uint4 q1 = *(const uint4*)(row + 8);
        uint4 k0 = *(const uint4*)(row + 128);
        uint4 k1 = *(const uint4*)(row + 136);
        uint4 v0 = *(const uint4*)(row + 256);
        uint4 v1 = *(const uint4*)(row + 264);
        *(uint4*)((unsigned short*)Qs + n * 16)     = q0;
        *(uint4*)((unsigned short*)Qs + n * 16 + 8) = q1;
        *(uint4*)((unsigned short*)Ks + n * 16)     = k0;
        *(uint4*)((unsigned short*)Ks + n * 16 + 8) = k1;
        union { uint4 u[2]; unsigned short s[16]; } vb;
        vb.u[0] = v0; vb.u[1] = v1;
        #pragma unroll
        for (int f = 0; f < 16; f++)
            ((unsigned short*)Vt)[f * 520 + n] = vb.s[f];
    }
    __syncthreads();

    const int lane = tid & 63;
    const int wv   = tid >> 6;
    const int l4   = lane & 15;
    const int g    = lane >> 4;
    const int qbase = wv * 128;
    const bf16* zp = Zero + (g & 1) * 8;
    const int p0 = ((l4 >> 2) << 3) | (l4 & 3);      // pi0 key permutation

    // Q fragments (B operand): col=query=l4, k=g*8 (groups 2,3 -> zeros)
    bf16x8 qf[8];
    #pragma unroll
    for (int qt = 0; qt < 8; qt++) {
        const bf16* ap = (g < 2) ? (Qs + (qbase + qt * 16 + l4) * 16 + g * 8) : zp;
        qf[qt] = *(const bf16x8*)ap;
    }

    f32x4 Oacc[8];
    float lsum[8];
    #pragma unroll
    for (int qt = 0; qt < 8; qt++) { Oacc[qt] = (f32x4){0.f,0.f,0.f,0.f}; lsum[qt] = 0.f; }

    const float cexp = 0.25f * 1.44269504088896f;   // scale * log2(e)

    for (int kt = 0; kt < 16; kt++) {               // 32 keys per iteration
        const bf16* k0p = (g < 2) ? (Ks + (kt * 32 + p0)     * 16 + g * 8) : zp;
        const bf16* k1p = (g < 2) ? (Ks + (kt * 32 + p0 + 4) * 16 + g * 8) : zp;
        bf16x8 kf0 = *(const bf16x8*)k0p;
        bf16x8 kf1 = *(const bf16x8*)k1p;
        bf16x8 vf  = *(const bf16x8*)(Vt + l4 * 520 + kt * 32 + g * 8);

        #pragma unroll
        for (int qt = 0; qt < 8; qt++) {
            f32x4 z = (f32x4){0.f,0.f,0.f,0.f};
            f32x4 s0 = __builtin_amdgcn_mfma_f32_16x16x32_bf16(kf0, qf[qt], z, 0, 0, 0);
            f32x4 s1 = __builtin_amdgcn_mfma_f32_16x16x32_bf16(kf1, qf[qt], z, 0, 0, 0);
            float e[8];
            #pragma unroll
            for (int r = 0; r < 4; r++) {
                e[r]     = exp2f(s0[r] * cexp);
                e[4 + r] = exp2f(s1[r] * cexp);
            }
            lsum[qt] += ((e[0]+e[1])+(e[2]+e[3])) + ((e[4]+e[5])+(e[6]+e[7]));
            bf16x8 pf;
            #pragma unroll
            for (int i = 0; i < 8; i++) pf[i] = f2bs(e[i]);
            Oacc[qt] = __builtin_amdgcn_mfma_f32_16x16x32_bf16(pf, vf, Oacc[qt], 0, 0, 0);
        }
    }

    // epilogue: reduce sums over lane-groups, scale, store
    #pragma unroll
    for (int qt = 0; qt < 8; qt++) {
        float ls = lsum[qt];
        ls += __shfl_xor(ls, 16);
        ls += __shfl_xor(ls, 32);
        #pragma unroll
        for (int r = 0; r < 4; r++) {
            float lq = __shfl(ls, g * 4 + r);            // full sum for query g*4+r
            float o = Oacc[qt][r] / lq;
            int qrow = t * 512 + qbase + qt * 16 + g * 4 + r;
            C[(size_t)qrow * 128 + h * 16 + l4] = __float2bfloat16(o);
        }
    }
}

// ---------------------------------------------------------------------------
// Stage-3 banded attention: window j in [i-7, i]. bf16 q/k/v in, bf16 out.
// ---------------------------------------------------------------------------
__global__ __launch_bounds__(256) void attn_banded_kernel(
    const bf16* __restrict__ Qkv, const bf16* __restrict__ Vb, bf16* __restrict__ C)
{
    __shared__ float Qs[TT][129];
    __shared__ float Ksh[TT][129];
    __shared__ float Vs[TT][129];
    const int n = blockIdx.x;
    const int tid = threadIdx.x;

    for (int e = tid; e < TT * DD; e += 256) {
        int t = e >> 7, d = e & 127;
        const bf16* row = Qkv + (size_t)(t * NN + n) * 384;
        Qs[t][d]  = __bfloat162float(row[d]);
        Ksh[t][d] = __bfloat162float(row[128 + d]);
        Vs[t][d]  = __bfloat162float(Vb[(size_t)(t * NN + n) * DD + d]);
    }
    __syncthreads();

    const int h = tid >> 5, i = tid & 31;
    const int hb = h * DH;

    float s[WND_];
    #pragma unroll
    for (int kk = 0; kk < WND_; kk++) {
        int j = i - (WND_ - 1) + kk;
        int jc = j < 0 ? 0 : j;
        float d = 0.f;
        #pragma unroll
        for (int f = 0; f < DH; f++) d += Qs[i][hb + f] * Ksh[jc][hb + f];
        s[kk] = (j >= 0) ? d * 0.25f : -1e30f;
    }
    float m = s[0];
    #pragma unroll
    for (int kk = 1; kk < WND_; kk++) m = fmaxf(m, s[kk]);
    float l = 0.f, p[WND_];
    #pragma unroll
    for (int kk = 0; kk < WND_; kk++) { p[kk] = __expf(s[kk] - m); l += p[kk]; }
    float inv = 1.f / l;
    float acc[DH] = {};
    #pragma unroll
    for (int kk = 0; kk < WND_; kk++) {
        int j = i - (WND_ - 1) + kk;
        int jc = j < 0 ? 0 : j;
        float pw = p[kk] * inv;
        #pragma unroll
        for (int f = 0; f < DH; f++) acc[f] += pw * Vs[jc][hb + f];
    }
    bf16* cp = C + (size_t)(i * NN + n) * DD + hb;
    #pragma unroll
    for (int f = 0; f < DH; f++) cp[f] = __float2bfloat16(acc[f]);
}

// ---------------------------------------------------------------------------
// LayerNorm over D=128, fp32 in -> bf16 out. One wave per token.
// ---------------------------------------------------------------------------
__global__ __launch_bounds__(256) void ln_kernel(
    const float* __restrict__ X, const float* __restrict__ g,
    const float* __restrict__ b, bf16* __restrict__ Y)
{
    const int token = blockIdx.x * 4 + (threadIdx.x >> 6);
    const int lane  = threadIdx.x & 63;
    const float* xr = X + (size_t)token * DD;
    float a0 = xr[lane], a1 = xr[lane + 64];
    float s = a0 + a1;
    #pragma unroll
    for (int off = 32; off > 0; off >>= 1) s += __shfl_xor(s, off);
    float mean = s * (1.0f / 128.0f);
    float d0 = a0 - mean, d1 = a1 - mean;
    float v = d0 * d0 + d1 * d1;
    #pragma unroll
    for (int off = 32; off > 0; off >>= 1) v += __shfl_xor(v, off);
    float rstd = rsqrtf(v * (1.0f / 128.0f) + 1e-5f);
    bf16* yr = Y + (size_t)token * DD;
    yr[lane]      = __float2bfloat16(d0 * rstd * g[lane]      + b[lane]);
    yr[lane + 64] = __float2bfloat16(d1 * rstd * g[lane + 64] + b[lane + 64]);
}

// ---------------------------------------------------------------------------
// time2vec: tiny table kernel (32x128) + BW-bound add kernel
// ---------------------------------------------------------------------------
__global__ __launch_bounds__(256) void t2v_table_kernel(
    const float* __restrict__ w, const float* __restrict__ b,
    const float* __restrict__ w0, const float* __restrict__ b0,
    float* __restrict__ tbl)
{
    int i = blockIdx.x * 256 + threadIdx.x;
    if (i < TT * DD) {
        int t = i >> 7, d = i & 127;
        float tau = (float)(t + 1);
        tbl[i] = (d < 127) ? sinf(tau * w[d] + b[d]) : (tau * w0[0] + b0[0]);
    }
}

__global__ __launch_bounds__(256) void t2v_add_kernel(
    const float* __restrict__ x, const float* __restrict__ tbl, bf16* __restrict__ Y)
{
    int i = blockIdx.x * 256 + threadIdx.x;     // group of 4 elems; total TOK*DD/4
    int e = i * 4;
    float4 xv = ((const float4*)x)[i];
    int ti = ((e >> 16) << 7) | (e & 127);
    float4 tv = *(const float4*)(tbl + ti);
    ushort4 o;
    o.x = (unsigned short)f2bs(xv.x + tv.x);
    o.y = (unsigned short)f2bs(xv.y + tv.y);
    o.z = (unsigned short)f2bs(xv.z + tv.z);
    o.w = (unsigned short)f2bs(xv.w + tv.w);
    *(ushort4*)((unsigned short*)Y + e) = o;
}

// ---------------------------------------------------------------------------
// Head: out[token] = dot(X[token,:], w). bf16 X, fp32 out.
// ---------------------------------------------------------------------------
__global__ __launch_bounds__(256) void head_kernel(
    const bf16* __restrict__ X, const float* __restrict__ w, float* __restrict__ out)
{
    const int token = blockIdx.x * 4 + (threadIdx.x >> 6);
    const int lane  = threadIdx.x & 63;
    const bf16* xr = X + (size_t)token * DD;
    float s = __bfloat162float(xr[lane]) * w[lane]
            + __bfloat162float(xr[lane + 64]) * w[lane + 64];
    #pragma unroll
    for (int off = 32; off > 0; off >>= 1) s += __shfl_xor(s, off);
    if (lane == 0) out[token] = s;
}

// ---------------------------------------------------------------------------

extern "C" void kernel_launch(void* const* d_in, const int* in_sizes, int n_in,
                              void* d_out, int out_size, void* d_ws, size_t ws_size,
                              hipStream_t stream) {
    const float* x           = (const float*)d_in[0];
    const float* enc_in_w    = (const float*)d_in[1];
    const float* enc_in_b    = (const float*)d_in[2];
    const float* enc_out_w   = (const float*)d_in[3];
    const float* enc_out_b   = (const float*)d_in[4];
    const float* enc_l1w     = (const float*)d_in[5];
    const float* enc_l1b     = (const float*)d_in[6];
    const float* enc_l2w     = (const float*)d_in[7];
    const float* enc_l2b     = (const float*)d_in[8];
    const float* enc_ln1w    = (const float*)d_in[9];
    const float* enc_ln1b    = (const float*)d_in[10];
    const float* enc_ln2w    = (const float*)d_in[11];
    const float* enc_ln2b    = (const float*)d_in[12];
    const float* qk_in_w     = (const float*)d_in[13];
    const float* qk_in_b     = (const float*)d_in[14];
    const float* qk_out_w    = (const float*)d_in[15];
    const float* qk_out_b    = (const float*)d_in[16];
    const float* qk_l1w      = (const float*)d_in[17];
    const float* qk_l1b      = (const float*)d_in[18];
    const float* qk_l2w      = (const float*)d_in[19];
    const float* qk_l2b      = (const float*)d_in[20];
    const float* qk_ln1w     = (const float*)d_in[21];
    const float* qk_ln1b     = (const float*)d_in[22];
    const float* qk_ln2w     = (const float*)d_in[23];
    const float* qk_ln2b     = (const float*)d_in[24];
    const float* t2v_w       = (const float*)d_in[25];
    const float* t2v_b       = (const float*)d_in[26];
    const float* t2v_w0      = (const float*)d_in[27];
    const float* t2v_b0      = (const float*)d_in[28];
    const float* out_w       = (const float*)d_in[29];
    float* out = (float*)d_out;

    // ---------------- workspace layout (bytes) ------------------------------
    char* ws = (char*)d_ws;
    const size_t TOKD = (size_t)TOK * DD;
    size_t off = 0;
    auto alloc = [&](size_t bytes) { char* p = ws + off; off += (bytes + 255) & ~(size_t)255; return p; };

    float* tmpB = (float*)alloc(TOKD * 4);               // pre-LN fp32
    bf16*  Qb   = (bf16*)alloc((size_t)TOK * 384 * 2);   // qkv bf16
    bf16*  Vb   = (bf16*)alloc(TOKD * 2);                // v-projection bf16
    bf16*  xb   = (bf16*)alloc(TOKD * 2);                // bf16 copy of x
    bf16*  bufA = (bf16*)alloc(TOKD * 2);                // residual stream bf16
    bf16*  Zb   = (bf16*)alloc(TOKD * 2);                // outs_zs bf16
    bf16*  Cb   = (bf16*)alloc(TOKD * 2);                // attn context bf16
    float* t2vt = (float*)alloc((size_t)TT * DD * 4);    // time2vec table
    bf16* enc_in_wb  = (bf16*)alloc(384 * DD * 2);
    bf16* enc_out_wb = (bf16*)alloc(DD * DD * 2);
    bf16* enc_l1wb   = (bf16*)alloc((size_t)FF_ * DD * 2);
    bf16* enc_l2wb   = (bf16*)alloc((size_t)DD * FF_ * 2);
    bf16* qk_in_wb   = (bf16*)alloc((size_t)LL * 384 * DD * 2);
    bf16* qk_out_wb  = (bf16*)alloc((size_t)LL * DD * DD * 2);
    bf16* qk_l1wb    = (bf16*)alloc((size_t)LL * FF_ * DD * 2);
    bf16* qk_l2wb    = (bf16*)alloc((size_t)LL * DD * FF_ * 2);
    bf16* Hb = (bf16*)(ws + off);
    size_t avail = ws_size > off ? ws_size - off : 0;
    int Mc = (int)((avail / ((size_t)FF_ * 2)) & ~(size_t)127);
    if (Mc > TOK) Mc = TOK;
    if (Mc < 128) Mc = 128;

    // ---------------- convert weights + x to bf16 ---------------------------
    auto conv = [&](const float* src, bf16* dst, size_t n) {
        int n4 = (int)(n / 4);
        f2b_kernel<<<(n4 + 255) / 256, 256, 0, stream>>>(src, dst, n4);
    };
    conv(x, xb, TOKD);
    conv(enc_in_w,  enc_in_wb,  384 * DD);
    conv(enc_out_w, enc_out_wb, DD * DD);
    conv(enc_l1w,   enc_l1wb,   (size_t)FF_ * DD);
    conv(enc_l2w,   enc_l2wb,   (size_t)DD * FF_);
    conv(qk_in_w,   qk_in_wb,   (size_t)LL * 384 * DD);
    conv(qk_out_w,  qk_out_wb,  (size_t)LL * DD * DD);
    conv(qk_l1w,    qk_l1wb,    (size_t)LL * FF_ * DD);
    conv(qk_l2w,    qk_l2wb,    (size_t)LL * DD * FF_);

    auto gemm128 = [&]<typename OutT>(const bf16* A, int lda, const bf16* W, const float* bias,
                       const bf16* R, OutT* C, int ldc, int M, int N, int K, int relu) {
        dim3 grid(N / 128, M / 128);
        mfma_gemm<128, 128, OutT><<<grid, 256, 0, stream>>>(A, lda, W, bias, R, C, ldc, K, relu);
    };
    auto gemm64 = [&]<typename OutT>(const bf16* A, int lda, const bf16* W, const float* bias,
                      const bf16* R, OutT* C, int ldc, int M, int N, int K, int relu) {
        dim3 grid(N / 64, M / 64);
        mfma_gemm<64, 64, OutT><<<grid, 256, 0, stream>>>(A, lda, W, bias, R, C, ldc, K, relu);
    };

    // ---------------- stage 1: plain encoder (attend over N, batch T) -------
    gemm128(xb, DD, enc_in_wb, enc_in_b, (const bf16*)nullptr, Qb, 384, TOK, 384, DD, 0);
    attn_full_mfma<<<TT * HH, 256, 0, stream>>>(Qb, Cb);
    gemm64(Cb, DD, enc_out_wb, enc_out_b, xb, tmpB, DD, TOK, DD, DD, 0);
    ln_kernel<<<TOK / 4, 256, 0, stream>>>(tmpB, enc_ln1w, enc_ln1b, bufA);
    for (int c0 = 0; c0 < TOK; c0 += Mc) {
        int cm = (TOK - c0) < Mc ? (TOK - c0) : Mc;
        gemm128(bufA + (size_t)c0 * DD, DD, enc_l1wb, enc_l1b, (const bf16*)nullptr, Hb, FF_, cm, FF_, DD, 1);
        gemm64(Hb, FF_, enc_l2wb, enc_l2b, bufA + (size_t)c0 * DD,
               tmpB + (size_t)c0 * DD, DD, cm, DD, FF_, 0);
    }
    ln_kernel<<<TOK / 4, 256, 0, stream>>>(tmpB, enc_ln2w, enc_ln2b, Zb);   // outs_zs

    // ---------------- stage 2: time2vec -------------------------------------
    t2v_table_kernel<<<(TT * DD + 255) / 256, 256, 0, stream>>>(t2v_w, t2v_b, t2v_w0, t2v_b0, t2vt);
    t2v_add_kernel<<<(TOK * DD / 4) / 256, 256, 0, stream>>>(x, t2vt, bufA);

    // ---------------- stage 3: qk encoder stack (banded window attn) ---------
    for (int l = 0; l < LL; l++) {
        const bf16* iw   = qk_in_wb  + (size_t)l * 384 * DD;
        const float* ib  = qk_in_b   + (size_t)l * 384;
        const bf16* owt  = qk_out_wb + (size_t)l * DD * DD;
        const float* ob  = qk_out_b  + (size_t)l * DD;
        const bf16* l1w  = qk_l1wb   + (size_t)l * FF_ * DD;
        const float* l1b = qk_l1b    + (size_t)l * FF_;
        const bf16* l2w  = qk_l2wb   + (size_t)l * DD * FF_;
        const float* l2b = qk_l2b    + (size_t)l * DD;

        gemm128(bufA, DD, iw, ib, (const bf16*)nullptr, Qb, 384, TOK, 256, DD, 0);
        gemm64(Zb, DD, iw + (size_t)256 * DD, ib + 256, (const bf16*)nullptr, Vb, DD, TOK, DD, DD, 0);
        attn_banded_kernel<<<NN, 256, 0, stream>>>(Qb, Vb, Cb);
        gemm64(Cb, DD, owt, ob, bufA, tmpB, DD, TOK, DD, DD, 0);
        ln_kernel<<<TOK / 4, 256, 0, stream>>>(tmpB, qk_ln1w + l * DD, qk_ln1b + l * DD, bufA);
        for (int c0 = 0; c0 < TOK; c0 += Mc) {
            int cm = (TOK - c0) < Mc ? (TOK - c0) : Mc;
            gemm128(bufA + (size_t)c0 * DD, DD, l1w, l1b, (const bf16*)nullptr, Hb, FF_, cm, FF_, DD, 1);
            gemm64(Hb, FF_, l2w, l2b, bufA + (size_t)c0 * DD,
                   tmpB + (size_t)c0 * DD, DD, cm, DD, FF_, 0);
        }
        ln_kernel<<<TOK / 4, 256, 0, stream>>>(tmpB, qk_ln2w + l * DD, qk_ln2b + l * DD, bufA);
    }

    // ---------------- head ----------------------------------------------------
    head_kernel<<<TOK / 4, 256, 0, stream>>>(bufA, out_w, out);
}

// Round 5
// 301.992 us; speedup vs baseline: 6.1982x; 1.2111x over previous
//
#include <hip/hip_runtime.h>
#include <hip/hip_bf16.h>
#include <math.h>

// Problem constants
#define TT 32
#define NN 512
#define DD 128
#define FF_ 2048
#define HH 8
#define LL 2
#define WND_ 8
#define TOK (TT*NN)          // 16384 tokens
#define DH 16                // head dim

typedef __hip_bfloat16 bf16;
typedef __attribute__((ext_vector_type(8))) short bf16x8;   // 8 bf16 (4 VGPRs)
typedef __attribute__((ext_vector_type(4))) float f32x4;    // 4 fp32

// global_load_lds: 16B per lane, LDS dest = wave-uniform base + lane*16 (linear)
#define GLD_LDS16(gp, lp) __builtin_amdgcn_global_load_lds( \
    (const __attribute__((address_space(1))) unsigned int*)(gp), \
    (__attribute__((address_space(3))) unsigned int*)(lp), 16, 0, 0)

__device__ inline short f2bs(float f) {
    __hip_bfloat16 h = __float2bfloat16(f);
    return *reinterpret_cast<short*>(&h);
}

// ---------------------------------------------------------------------------
// bf16 MFMA GEMM: C[M,N] = A[M,K] @ W[N,K]^T + bias (+relu). Output bf16.
// Tile BM x BN, BK=32, 256 threads = 4 waves in 2x2.
// ---------------------------------------------------------------------------
template<int BM, int BN>
__global__ __launch_bounds__(256) void mfma_gemm(
    const bf16* __restrict__ A, int lda,
    const bf16* __restrict__ W,              // [N,K] row-major (= B^T)
    const float* __restrict__ bias,          // [N]
    bf16* __restrict__ C, int ldc,
    int K, int relu)
{
    constexpr int WM = BM / 2, WN = BN / 2;
    constexpr int FM = WM / 16, FN = WN / 16;
    constexpr int LA = (BM * 64) / (256 * 16);
    constexpr int LB = (BN * 64) / (256 * 16);

    __shared__ bf16 As[BM * 32];
    __shared__ bf16 Bs[BN * 32];

    const int tid  = threadIdx.x;
    const int lane = tid & 63;
    const int wave = tid >> 6;
    const int wm = wave >> 1, wn = wave & 1;
    const int bm = blockIdx.y * BM, bn = blockIdx.x * BN;

    f32x4 acc[FM][FN];
    #pragma unroll
    for (int m = 0; m < FM; m++)
        #pragma unroll
        for (int n = 0; n < FN; n++)
            acc[m][n] = (f32x4){0.f, 0.f, 0.f, 0.f};

    for (int k0 = 0; k0 < K; k0 += 32) {
        #pragma unroll
        for (int i = 0; i < LA; i++) {
            const int o = (tid + i * 256) * 16;
            const int row = o >> 6;
            const int ce  = (o & 63) >> 1;
            GLD_LDS16(A + (size_t)(bm + row) * lda + k0 + ce, (char*)As + o);
        }
        #pragma unroll
        for (int i = 0; i < LB; i++) {
            const int o = (tid + i * 256) * 16;
            const int row = o >> 6;
            const int ce  = (o & 63) >> 1;
            GLD_LDS16(W + (size_t)(bn + row) * K + k0 + ce, (char*)Bs + o);
        }
        __syncthreads();

        bf16x8 af[FM], bfr[FN];
        #pragma unroll
        for (int m = 0; m < FM; m++)
            af[m] = *(const bf16x8*)(As + (wm * WM + m * 16 + (lane & 15)) * 32 + (lane >> 4) * 8);
        #pragma unroll
        for (int n = 0; n < FN; n++)
            bfr[n] = *(const bf16x8*)(Bs + (wn * WN + n * 16 + (lane & 15)) * 32 + (lane >> 4) * 8);
        #pragma unroll
        for (int m = 0; m < FM; m++)
            #pragma unroll
            for (int n = 0; n < FN; n++)
                acc[m][n] = __builtin_amdgcn_mfma_f32_16x16x32_bf16(af[m], bfr[n], acc[m][n], 0, 0, 0);
        __syncthreads();
    }

    // C/D layout: col = lane&15, row = (lane>>4)*4 + reg
    #pragma unroll
    for (int n = 0; n < FN; n++) {
        const int col = bn + wn * WN + n * 16 + (lane & 15);
        const float bv = bias[col];
        #pragma unroll
        for (int m = 0; m < FM; m++) {
            #pragma unroll
            for (int r = 0; r < 4; r++) {
                const int row = bm + wm * WM + m * 16 + (lane >> 4) * 4 + r;
                float v = acc[m][n][r] + bv;
                if (relu) v = fmaxf(v, 0.f);
                C[(size_t)row * ldc + col] = __float2bfloat16(v);
            }
        }
    }
}

// ---------------------------------------------------------------------------
// Fused GEMM + bias + residual + LayerNorm (+ optional head dot-product).
// Fixed BM=64, BN=128 (N must be 128 = full LN row). 256 threads, waves 2x2,
// each wave 32x64. Row sums via in-lane + shfl_xor(1,2,4,8) + 2-wave LDS.
// HEAD: instead of storing Y, compute out[row] = dot(ln_row, hw).
// ---------------------------------------------------------------------------
template<bool HEAD>
__global__ __launch_bounds__(256) void mfma_gemm_ln(
    const bf16* __restrict__ A, int lda,
    const bf16* __restrict__ W,              // [128,K]
    const float* __restrict__ bias,          // [128]
    const bf16* __restrict__ R,              // residual [M,128] bf16
    const float* __restrict__ lng, const float* __restrict__ lnb,
    bf16* __restrict__ Y,                    // [M,128] bf16 (unused if HEAD)
    const float* __restrict__ hw, float* __restrict__ hout,  // head (HEAD only)
    int K)
{
    constexpr int BM = 64, BN = 128, WM = 32, WN = 64, FM = 2, FN = 4;

    __shared__ bf16 As[BM * 32];
    __shared__ bf16 Bs[BN * 32];
    __shared__ float rsum[BM][2];
    __shared__ float rsq[BM][2];

    const int tid  = threadIdx.x;
    const int lane = tid & 63;
    const int wave = tid >> 6;
    const int wm = wave >> 1, wn = wave & 1;
    const int bm = blockIdx.x * BM;

    f32x4 acc[FM][FN];
    #pragma unroll
    for (int m = 0; m < FM; m++)
        #pragma unroll
        for (int n = 0; n < FN; n++)
            acc[m][n] = (f32x4){0.f, 0.f, 0.f, 0.f};

    for (int k0 = 0; k0 < K; k0 += 32) {
        {   // A tile: 64 rows x 32 cols = 4096 B, 1 load/thread
            const int o = tid * 16;
            const int row = o >> 6;
            const int ce  = (o & 63) >> 1;
            GLD_LDS16(A + (size_t)(bm + row) * lda + k0 + ce, (char*)As + o);
        }
        #pragma unroll
        for (int i = 0; i < 2; i++) {       // B tile: 128 rows
            const int o = (tid + i * 256) * 16;
            const int row = o >> 6;
            const int ce  = (o & 63) >> 1;
            GLD_LDS16(W + (size_t)row * K + k0 + ce, (char*)Bs + o);
        }
        __syncthreads();

        bf16x8 af[FM], bfr[FN];
        #pragma unroll
        for (int m = 0; m < FM; m++)
            af[m] = *(const bf16x8*)(As + (wm * WM + m * 16 + (lane & 15)) * 32 + (lane >> 4) * 8);
        #pragma unroll
        for (int n = 0; n < FN; n++)
            bfr[n] = *(const bf16x8*)(Bs + (wn * WN + n * 16 + (lane & 15)) * 32 + (lane >> 4) * 8);
        #pragma unroll
        for (int m = 0; m < FM; m++)
            #pragma unroll
            for (int n = 0; n < FN; n++)
                acc[m][n] = __builtin_amdgcn_mfma_f32_16x16x32_bf16(af[m], bfr[n], acc[m][n], 0, 0, 0);
        __syncthreads();
    }

    // finalize: bias + residual
    #pragma unroll
    for (int n = 0; n < FN; n++) {
        const int col = wn * WN + n * 16 + (lane & 15);
        const float bv = bias[col];
        #pragma unroll
        for (int m = 0; m < FM; m++) {
            #pragma unroll
            for (int r = 0; r < 4; r++) {
                const int rl = wm * WM + m * 16 + (lane >> 4) * 4 + r;
                acc[m][n][r] += bv + __bfloat162float(R[(size_t)(bm + rl) * 128 + col]);
            }
        }
    }

    // row sums (each 16-lane group owns one row per (m,r))
    #pragma unroll
    for (int m = 0; m < FM; m++) {
        #pragma unroll
        for (int r = 0; r < 4; r++) {
            float s = 0.f, q = 0.f;
            #pragma unroll
            for (int n = 0; n < FN; n++) { float v = acc[m][n][r]; s += v; q += v * v; }
            #pragma unroll
            for (int off = 1; off < 16; off <<= 1) {
                s += __shfl_xor(s, off);
                q += __shfl_xor(q, off);
            }
            const int rl = wm * WM + m * 16 + (lane >> 4) * 4 + r;
            if ((lane & 15) == 0) { rsum[rl][wn] = s; rsq[rl][wn] = q; }
        }
    }
    __syncthreads();

    float hacc[FM][4];
    #pragma unroll
    for (int m = 0; m < FM; m++)
        #pragma unroll
        for (int r = 0; r < 4; r++) hacc[m][r] = 0.f;

    #pragma unroll
    for (int m = 0; m < FM; m++) {
        #pragma unroll
        for (int r = 0; r < 4; r++) {
            const int rl = wm * WM + m * 16 + (lane >> 4) * 4 + r;
            const float S = rsum[rl][0] + rsum[rl][1];
            const float Q = rsq[rl][0] + rsq[rl][1];
            const float mean = S * (1.0f / 128.0f);
            const float var  = Q * (1.0f / 128.0f) - mean * mean;
            const float rstd = rsqrtf(var + 1e-5f);
            #pragma unroll
            for (int n = 0; n < FN; n++) {
                const int col = wn * WN + n * 16 + (lane & 15);
                const float y = (acc[m][n][r] - mean) * rstd * lng[col] + lnb[col];
                if (HEAD) hacc[m][r] += y * hw[col];
                else Y[(size_t)(bm + rl) * 128 + col] = __float2bfloat16(y);
            }
        }
    }

    if (HEAD) {
        __syncthreads();   // reuse rsum
        #pragma unroll
        for (int m = 0; m < FM; m++) {
            #pragma unroll
            for (int r = 0; r < 4; r++) {
                float h = hacc[m][r];
                #pragma unroll
                for (int off = 1; off < 16; off <<= 1) h += __shfl_xor(h, off);
                const int rl = wm * WM + m * 16 + (lane >> 4) * 4 + r;
                if ((lane & 15) == 0) rsum[rl][wn] = h;
            }
        }
        __syncthreads();
        if (tid < BM) hout[bm + tid] = rsum[tid][0] + rsum[tid][1];
    }
}

// ---------------------------------------------------------------------------
// Merged fp32->bf16 conversion of all weights + x, plus t2v table (segment 9).
// Grid-strided over float4 groups; compile-time segment boundaries.
// ---------------------------------------------------------------------------
struct ConvDesc {
    const float *x, *s1, *s2, *s3, *s4, *s5, *s6, *s7, *s8;
    bf16 *dx, *d1, *d2, *d3, *d4, *d5, *d6, *d7, *d8;
    const float *w, *b, *w0, *b0;
    float* tbl;
};

__device__ inline void cvt4(const float* s, bf16* d, int j) {
    float4 v = ((const float4*)s)[j];
    ushort4 o;
    o.x = (unsigned short)f2bs(v.x); o.y = (unsigned short)f2bs(v.y);
    o.z = (unsigned short)f2bs(v.z); o.w = (unsigned short)f2bs(v.w);
    *(ushort4*)((unsigned short*)d + j * 4) = o;
}

// prefix sums in float4 units
#define CP0 524288   // x            (2097152)
#define CP1 536576   // enc_in_w     (49152)
#define CP2 540672   // enc_out_w    (16384)
#define CP3 606208   // enc_l1w      (262144)
#define CP4 671744   // enc_l2w      (262144)
#define CP5 696320   // qk_in_w      (98304)
#define CP6 704512   // qk_out_w     (32768)
#define CP7 835584   // qk_l1w       (524288)
#define CP8 966656   // qk_l2w       (524288)
#define CP9 967680   // t2v table    (4096 fp32)

__global__ __launch_bounds__(256) void conv_all_kernel(ConvDesc cd)
{
    int i = blockIdx.x * 256 + threadIdx.x;
    if (i < CP0)      cvt4(cd.x,  cd.dx, i);
    else if (i < CP1) cvt4(cd.s1, cd.d1, i - CP0);
    else if (i < CP2) cvt4(cd.s2, cd.d2, i - CP1);
    else if (i < CP3) cvt4(cd.s3, cd.d3, i - CP2);
    else if (i < CP4) cvt4(cd.s4, cd.d4, i - CP3);
    else if (i < CP5) cvt4(cd.s5, cd.d5, i - CP4);
    else if (i < CP6) cvt4(cd.s6, cd.d6, i - CP5);
    else if (i < CP7) cvt4(cd.s7, cd.d7, i - CP6);
    else if (i < CP8) cvt4(cd.s8, cd.d8, i - CP7);
    else if (i < CP9) {
        int e = (i - CP8) * 4;
        int t = e >> 7;
        float tau = (float)(t + 1);
        float4 o;
        #pragma unroll
        for (int k = 0; k < 4; k++) {
            int d = (e + k) & 127;
            ((float*)&o)[k] = (d < 127) ? sinf(tau * cd.w[d] + cd.b[d])
                                        : (tau * cd.w0[0] + cd.b0[0]);
        }
        *(float4*)(cd.tbl + e) = o;
    }
}

// ---------------------------------------------------------------------------
// Stage-1 attention via MFMA (flash, maxless). One block per (t,h).
// ---------------------------------------------------------------------------
__global__ __launch_bounds__(256) void attn_full_mfma(
    const bf16* __restrict__ Qkv, bf16* __restrict__ C)
{
    __shared__ bf16 Qs[512 * 16];
    __shared__ bf16 Ks[512 * 16];
    __shared__ bf16 Vt[16 * 520];
    __shared__ bf16 Zero[32];          // 64B broadcast zero block

    const int t = blockIdx.x >> 3;
    const int h = blockIdx.x & 7;
    const int tid = threadIdx.x;

    if (tid < 32) ((unsigned short*)Zero)[tid] = 0;

    for (int n = tid; n < 512; n += 256) {
        const unsigned short* row = (const unsigned short*)Qkv + (size_t)(t * 512 + n) * 384 + h * 16;
        uint4 q0 = *(const uint4*)(row);
        uint4 q1 = *(const uint4*)(row + 8);
        uint4 k0 = *(const uint4*)(row + 128);
        uint4 k1 = *(const uint4*)(row + 136);
        uint4 v0 = *(const uint4*)(row + 256);
        uint4 v1 = *(const uint4*)(row + 264);
        *(uint4*)((unsigned short*)Qs + n * 16)     = q0;
        *(uint4*)((unsigned short*)Qs + n * 16 + 8) = q1;
        *(uint4*)((unsigned short*)Ks + n * 16)     = k0;
        *(uint4*)((unsigned short*)Ks + n * 16 + 8) = k1;
        union { uint4 u[2]; unsigned short s[16]; } vb;
        vb.u[0] = v0; vb.u[1] = v1;
        #pragma unroll
        for (int f = 0; f < 16; f++)
            ((unsigned short*)Vt)[f * 520 + n] = vb.s[f];
    }
    __syncthreads();

    const int lane = tid & 63;
    const int wv   = tid >> 6;
    const int l4   = lane & 15;
    const int g    = lane >> 4;
    const int qbase = wv * 128;
    const bf16* zp = Zero + (g & 1) * 8;
    const int p0 = ((l4 >> 2) << 3) | (l4 & 3);      // pi0 key permutation

    bf16x8 qf[8];
    #pragma unroll
    for (int qt = 0; qt < 8; qt++) {
        const bf16* ap = (g < 2) ? (Qs + (qbase + qt * 16 + l4) * 16 + g * 8) : zp;
        qf[qt] = *(const bf16x8*)ap;
    }

    f32x4 Oacc[8];
    float lsum[8];
    #pragma unroll
    for (int qt = 0; qt < 8; qt++) { Oacc[qt] = (f32x4){0.f,0.f,0.f,0.f}; lsum[qt] = 0.f; }

    const float cexp = 0.25f * 1.44269504088896f;   // scale * log2(e)

    for (int kt = 0; kt < 16; kt++) {               // 32 keys per iteration
        const bf16* k0p = (g < 2) ? (Ks + (kt * 32 + p0)     * 16 + g * 8) : zp;
        const bf16* k1p = (g < 2) ? (Ks + (kt * 32 + p0 + 4) * 16 + g * 8) : zp;
        bf16x8 kf0 = *(const bf16x8*)k0p;
        bf16x8 kf1 = *(const bf16x8*)k1p;
        bf16x8 vf  = *(const bf16x8*)(Vt + l4 * 520 + kt * 32 + g * 8);

        #pragma unroll
        for (int qt = 0; qt < 8; qt++) {
            f32x4 z = (f32x4){0.f,0.f,0.f,0.f};
            f32x4 s0 = __builtin_amdgcn_mfma_f32_16x16x32_bf16(kf0, qf[qt], z, 0, 0, 0);
            f32x4 s1 = __builtin_amdgcn_mfma_f32_16x16x32_bf16(kf1, qf[qt], z, 0, 0, 0);
            float e[8];
            #pragma unroll
            for (int r = 0; r < 4; r++) {
                e[r]     = exp2f(s0[r] * cexp);
                e[4 + r] = exp2f(s1[r] * cexp);
            }
            lsum[qt] += ((e[0]+e[1])+(e[2]+e[3])) + ((e[4]+e[5])+(e[6]+e[7]));
            bf16x8 pf;
            #pragma unroll
            for (int i = 0; i < 8; i++) pf[i] = f2bs(e[i]);
            Oacc[qt] = __builtin_amdgcn_mfma_f32_16x16x32_bf16(pf, vf, Oacc[qt], 0, 0, 0);
        }
    }

    #pragma unroll
    for (int qt = 0; qt < 8; qt++) {
        float ls = lsum[qt];
        ls += __shfl_xor(ls, 16);
        ls += __shfl_xor(ls, 32);
        #pragma unroll
        for (int r = 0; r < 4; r++) {
            float lq = __shfl(ls, g * 4 + r);
            float o = Oacc[qt][r] / lq;
            int qrow = t * 512 + qbase + qt * 16 + g * 4 + r;
            C[(size_t)qrow * 128 + h * 16 + l4] = __float2bfloat16(o);
        }
    }
}

// ---------------------------------------------------------------------------
// Stage-3 banded attention: window j in [i-7, i]. bf16 q/k/v in, bf16 out.
// ---------------------------------------------------------------------------
__global__ __launch_bounds__(256) void attn_banded_kernel(
    const bf16* __restrict__ Qkv, const bf16* __restrict__ Vb, bf16* __restrict__ C)
{
    __shared__ float Qs[TT][129];
    __shared__ float Ksh[TT][129];
    __shared__ float Vs[TT][129];
    const int n = blockIdx.x;
    const int tid = threadIdx.x;

    for (int e = tid; e < TT * DD; e += 256) {
        int t = e >> 7, d = e & 127;
        const bf16* row = Qkv + (size_t)(t * NN + n) * 384;
        Qs[t][d]  = __bfloat162float(row[d]);
        Ksh[t][d] = __bfloat162float(row[128 + d]);
        Vs[t][d]  = __bfloat162float(Vb[(size_t)(t * NN + n) * DD + d]);
    }
    __syncthreads();

    const int h = tid >> 5, i = tid & 31;
    const int hb = h * DH;

    float s[WND_];
    #pragma unroll
    for (int kk = 0; kk < WND_; kk++) {
        int j = i - (WND_ - 1) + kk;
        int jc = j < 0 ? 0 : j;
        float d = 0.f;
        #pragma unroll
        for (int f = 0; f < DH; f++) d += Qs[i][hb + f] * Ksh[jc][hb + f];
        s[kk] = (j >= 0) ? d * 0.25f : -1e30f;
    }
    float m = s[0];
    #pragma unroll
    for (int kk = 1; kk < WND_; kk++) m = fmaxf(m, s[kk]);
    float l = 0.f, p[WND_];
    #pragma unroll
    for (int kk = 0; kk < WND_; kk++) { p[kk] = __expf(s[kk] - m); l += p[kk]; }
    float inv = 1.f / l;
    float acc[DH] = {};
    #pragma unroll
    for (int kk = 0; kk < WND_; kk++) {
        int j = i - (WND_ - 1) + kk;
        int jc = j < 0 ? 0 : j;
        float pw = p[kk] * inv;
        #pragma unroll
        for (int f = 0; f < DH; f++) acc[f] += pw * Vs[jc][hb + f];
    }
    bf16* cp = C + (size_t)(i * NN + n) * DD + hb;
    #pragma unroll
    for (int f = 0; f < DH; f++) cp[f] = __float2bfloat16(acc[f]);
}

// ---------------------------------------------------------------------------
// time2vec add: Y = bf16(x + tbl[t, d])
// ---------------------------------------------------------------------------
__global__ __launch_bounds__(256) void t2v_add_kernel(
    const float* __restrict__ x, const float* __restrict__ tbl, bf16* __restrict__ Y)
{
    int i = blockIdx.x * 256 + threadIdx.x;     // float4 groups
    int e = i * 4;
    float4 xv = ((const float4*)x)[i];
    int ti = ((e >> 16) << 7) | (e & 127);
    float4 tv = *(const float4*)(tbl + ti);
    ushort4 o;
    o.x = (unsigned short)f2bs(xv.x + tv.x);
    o.y = (unsigned short)f2bs(xv.y + tv.y);
    o.z = (unsigned short)f2bs(xv.z + tv.z);
    o.w = (unsigned short)f2bs(xv.w + tv.w);
    *(ushort4*)((unsigned short*)Y + e) = o;
}

// ---------------------------------------------------------------------------

extern "C" void kernel_launch(void* const* d_in, const int* in_sizes, int n_in,
                              void* d_out, int out_size, void* d_ws, size_t ws_size,
                              hipStream_t stream) {
    const float* x           = (const float*)d_in[0];
    const float* enc_in_w    = (const float*)d_in[1];
    const float* enc_in_b    = (const float*)d_in[2];
    const float* enc_out_w   = (const float*)d_in[3];
    const float* enc_out_b   = (const float*)d_in[4];
    const float* enc_l1w     = (const float*)d_in[5];
    const float* enc_l1b     = (const float*)d_in[6];
    const float* enc_l2w     = (const float*)d_in[7];
    const float* enc_l2b     = (const float*)d_in[8];
    const float* enc_ln1w    = (const float*)d_in[9];
    const float* enc_ln1b    = (const float*)d_in[10];
    const float* enc_ln2w    = (const float*)d_in[11];
    const float* enc_ln2b    = (const float*)d_in[12];
    const float* qk_in_w     = (const float*)d_in[13];
    const float* qk_in_b     = (const float*)d_in[14];
    const float* qk_out_w    = (const float*)d_in[15];
    const float* qk_out_b    = (const float*)d_in[16];
    const float* qk_l1w      = (const float*)d_in[17];
    const float* qk_l1b      = (const float*)d_in[18];
    const float* qk_l2w      = (const float*)d_in[19];
    const float* qk_l2b      = (const float*)d_in[20];
    const float* qk_ln1w     = (const float*)d_in[21];
    const float* qk_ln1b     = (const float*)d_in[22];
    const float* qk_ln2w     = (const float*)d_in[23];
    const float* qk_ln2b     = (const float*)d_in[24];
    const float* t2v_w       = (const float*)d_in[25];
    const float* t2v_b       = (const float*)d_in[26];
    const float* t2v_w0      = (const float*)d_in[27];
    const float* t2v_b0      = (const float*)d_in[28];
    const float* out_w       = (const float*)d_in[29];
    float* out = (float*)d_out;

    // ---------------- workspace layout (bytes) ------------------------------
    char* ws = (char*)d_ws;
    const size_t TOKD = (size_t)TOK * DD;
    size_t off = 0;
    auto alloc = [&](size_t bytes) { char* p = ws + off; off += (bytes + 255) & ~(size_t)255; return p; };

    bf16*  Qb   = (bf16*)alloc((size_t)TOK * 384 * 2);   // qkv bf16
    bf16*  Vb   = (bf16*)alloc(TOKD * 2);                // v-projection bf16
    bf16*  xb   = (bf16*)alloc(TOKD * 2);                // bf16 copy of x
    bf16*  bufA = (bf16*)alloc(TOKD * 2);                // residual stream bf16
    bf16*  Zb   = (bf16*)alloc(TOKD * 2);                // outs_zs bf16
    bf16*  Cb   = (bf16*)alloc(TOKD * 2);                // attn context bf16
    float* t2vt = (float*)alloc((size_t)TT * DD * 4);    // time2vec table
    bf16* enc_in_wb  = (bf16*)alloc(384 * DD * 2);
    bf16* enc_out_wb = (bf16*)alloc(DD * DD * 2);
    bf16* enc_l1wb   = (bf16*)alloc((size_t)FF_ * DD * 2);
    bf16* enc_l2wb   = (bf16*)alloc((size_t)DD * FF_ * 2);
    bf16* qk_in_wb   = (bf16*)alloc((size_t)LL * 384 * DD * 2);
    bf16* qk_out_wb  = (bf16*)alloc((size_t)LL * DD * DD * 2);
    bf16* qk_l1wb    = (bf16*)alloc((size_t)LL * FF_ * DD * 2);
    bf16* qk_l2wb    = (bf16*)alloc((size_t)LL * DD * FF_ * 2);
    bf16* Hb = (bf16*)(ws + off);                        // FFN hidden chunk (bf16)
    size_t avail = ws_size > off ? ws_size - off : 0;
    int Mc = (int)((avail / ((size_t)FF_ * 2)) & ~(size_t)127);
    if (Mc > TOK) Mc = TOK;
    if (Mc < 128) Mc = 128;

    // ---------------- one-shot conversion of all weights + x + t2v table ----
    ConvDesc cd;
    cd.x  = x;        cd.dx = xb;
    cd.s1 = enc_in_w; cd.d1 = enc_in_wb;
    cd.s2 = enc_out_w;cd.d2 = enc_out_wb;
    cd.s3 = enc_l1w;  cd.d3 = enc_l1wb;
    cd.s4 = enc_l2w;  cd.d4 = enc_l2wb;
    cd.s5 = qk_in_w;  cd.d5 = qk_in_wb;
    cd.s6 = qk_out_w; cd.d6 = qk_out_wb;
    cd.s7 = qk_l1w;   cd.d7 = qk_l1wb;
    cd.s8 = qk_l2w;   cd.d8 = qk_l2wb;
    cd.w = t2v_w; cd.b = t2v_b; cd.w0 = t2v_w0; cd.b0 = t2v_b0; cd.tbl = t2vt;
    conv_all_kernel<<<(CP9 + 255) / 256, 256, 0, stream>>>(cd);

    auto gemm128 = [&](const bf16* A, int lda, const bf16* W, const float* bias,
                       bf16* C, int ldc, int M, int N, int K, int relu) {
        dim3 grid(N / 128, M / 128);
        mfma_gemm<128, 128><<<grid, 256, 0, stream>>>(A, lda, W, bias, C, ldc, K, relu);
    };
    auto gemm64 = [&](const bf16* A, int lda, const bf16* W, const float* bias,
                      bf16* C, int ldc, int M, int N, int K, int relu) {
        dim3 grid(N / 64, M / 64);
        mfma_gemm<64, 64><<<grid, 256, 0, stream>>>(A, lda, W, bias, C, ldc, K, relu);
    };
    auto gemm_ln = [&](const bf16* A, int lda, const bf16* W, const float* bias,
                       const bf16* R, const float* lng, const float* lnb,
                       bf16* Y, int M, int K) {
        mfma_gemm_ln<false><<<M / 64, 256, 0, stream>>>(A, lda, W, bias, R, lng, lnb,
                                                        Y, nullptr, nullptr, K);
    };
    auto gemm_ln_head = [&](const bf16* A, int lda, const bf16* W, const float* bias,
                            const bf16* R, const float* lng, const float* lnb,
                            const float* hw, float* hout, int M, int K) {
        mfma_gemm_ln<true><<<M / 64, 256, 0, stream>>>(A, lda, W, bias, R, lng, lnb,
                                                       nullptr, hw, hout, K);
    };

    // ---------------- stage 1: plain encoder (attend over N, batch T) -------
    gemm128(xb, DD, enc_in_wb, enc_in_b, Qb, 384, TOK, 384, DD, 0);
    attn_full_mfma<<<TT * HH, 256, 0, stream>>>(Qb, Cb);
    gemm_ln(Cb, DD, enc_out_wb, enc_out_b, xb, enc_ln1w, enc_ln1b, bufA, TOK, DD);
    for (int c0 = 0; c0 < TOK; c0 += Mc) {
        int cm = (TOK - c0) < Mc ? (TOK - c0) : Mc;
        gemm128(bufA + (size_t)c0 * DD, DD, enc_l1wb, enc_l1b, Hb, FF_, cm, FF_, DD, 1);
        gemm_ln(Hb, FF_, enc_l2wb, enc_l2b, bufA + (size_t)c0 * DD,
                enc_ln2w, enc_ln2b, Zb + (size_t)c0 * DD, cm, FF_);
    }

    // ---------------- stage 2: time2vec -------------------------------------
    t2v_add_kernel<<<(TOK * DD / 4) / 256, 256, 0, stream>>>(x, t2vt, bufA);

    // ---------------- stage 3: qk encoder stack (banded window attn) ---------
    for (int l = 0; l < LL; l++) {
        const bf16* iw   = qk_in_wb  + (size_t)l * 384 * DD;
        const float* ib  = qk_in_b   + (size_t)l * 384;
        const bf16* owt  = qk_out_wb + (size_t)l * DD * DD;
        const float* ob  = qk_out_b  + (size_t)l * DD;
        const bf16* l1w  = qk_l1wb   + (size_t)l * FF_ * DD;
        const float* l1b = qk_l1b    + (size_t)l * FF_;
        const bf16* l2w  = qk_l2wb   + (size_t)l * DD * FF_;
        const float* l2b = qk_l2b    + (size_t)l * DD;

        gemm128(bufA, DD, iw, ib, Qb, 384, TOK, 256, DD, 0);
        gemm64(Zb, DD, iw + (size_t)256 * DD, ib + 256, Vb, DD, TOK, DD, DD, 0);
        attn_banded_kernel<<<NN, 256, 0, stream>>>(Qb, Vb, Cb);
        gemm_ln(Cb, DD, owt, ob, bufA, qk_ln1w + l * DD, qk_ln1b + l * DD, bufA, TOK, DD);
        for (int c0 = 0; c0 < TOK; c0 += Mc) {
            int cm = (TOK - c0) < Mc ? (TOK - c0) : Mc;
            gemm128(bufA + (size_t)c0 * DD, DD, l1w, l1b, Hb, FF_, cm, FF_, DD, 1);
            if (l == LL - 1) {
                gemm_ln_head(Hb, FF_, l2w, l2b, bufA + (size_t)c0 * DD,
                             qk_ln2w + l * DD, qk_ln2b + l * DD,
                             out_w, out + c0, cm, FF_);
            } else {
                gemm_ln(Hb, FF_, l2w, l2b, bufA + (size_t)c0 * DD,
                        qk_ln2w + l * DD, qk_ln2b + l * DD,
                        bufA + (size_t)c0 * DD, cm, FF_);
            }
        }
    }
}